// Round 1
// baseline (140.564 us; speedup 1.0000x reference)
//
#include <hip/hip_runtime.h>

#define N 8192
#define G 256
#define D 64
#define H 128
#define CAP 8

// ---- workspace word offsets ----
#define OFF_EGRID   0
#define OFF_RGRID   65536
#define OFF_TMP     131072
#define OFF_FIELD   196608
#define OFF_A       262144     // 8192*64
#define OFF_HBUF    786432     // 8192*128
#define OFF_POT     1835008
#define OFF_OUTSUM  1843200
#define OFF_INSUM   1851392
#define OFF_NNBR    1859584
#define OFF_MASSN   1867776
#define OFF_FIN     1875968
#define OFF_TGT     1884160
#define OFF_CELLCNT 1892352
#define OFF_BUCKET  1957888    // 65536*CAP -> end 2482176 words (~9.5 MB)

__global__ void k_zero(float* eg, float* rg, int* cellcnt) {
    int i = blockIdx.x * blockDim.x + threadIdx.x;
    if (i < G * G) { eg[i] = 0.f; rg[i] = 0.f; cellcnt[i] = 0; }
}

__global__ void k_scatter(const int* pos, const int* roles, const float* energies,
                          float* eg, float* rg, int* cellcnt, int* bucket) {
    int i = blockIdx.x * blockDim.x + threadIdx.x;
    if (i >= N) return;
    int x = pos[2 * i], y = pos[2 * i + 1];
    int c = y * G + x;
    atomicMax((int*)&eg[c], __float_as_int(energies[i]));          // non-negative floats
    atomicMax((int*)&rg[c], __float_as_int((float)roles[i]));
    int slot = atomicAdd(&cellcnt[c], 1);
    if (slot < CAP) bucket[c * CAP + slot] = i;
}

__global__ void k_sortbuckets(int* cellcnt, int* bucket) {
    int c = blockIdx.x * blockDim.x + threadIdx.x;
    if (c >= G * G) return;
    int n = cellcnt[c]; if (n > CAP) n = CAP;
    cellcnt[c] = n;
    for (int a = 1; a < n; a++) {
        int v = bucket[c * CAP + a];
        int b = a - 1;
        while (b >= 0 && bucket[c * CAP + b] > v) { bucket[c * CAP + b + 1] = bucket[c * CAP + b]; b--; }
        bucket[c * CAP + b + 1] = v;
    }
}

__device__ __forceinline__ void gauss_weights(float* k) {
    float s = 0.f;
    #pragma unroll
    for (int m = 0; m < 15; m++) { float xx = (float)m - 7.f; k[m] = __expf(0.f) * expf(-(xx * xx) / 8.f); s += k[m]; }
    #pragma unroll
    for (int m = 0; m < 15; m++) k[m] /= s;
}

__global__ void k_blurV(const float* eg, const float* rg, float* tmp) {
    int idx = blockIdx.x * blockDim.x + threadIdx.x;
    if (idx >= G * G) return;
    int x = idx & (G - 1), y = idx >> 8;
    float k[15]; gauss_weights(k);
    float acc = 0.f;
    #pragma unroll
    for (int m = 0; m < 15; m++) {
        int yy = y + m - 7;
        if ((unsigned)yy < G) {
            float img = eg[yy * G + x] + 0.5f * rg[yy * G + x];
            acc += img * k[m];
        }
    }
    tmp[idx] = acc;
}

__global__ void k_blurH(const float* tmp, float* field) {
    int idx = blockIdx.x * blockDim.x + threadIdx.x;
    if (idx >= G * G) return;
    int x = idx & (G - 1), y = idx >> 8;
    float k[15]; gauss_weights(k);
    float acc = 0.f;
    #pragma unroll
    for (int m = 0; m < 15; m++) {
        int xx = x + m - 7;
        if ((unsigned)xx < G) acc += tmp[y * G + xx] * k[m];
    }
    field[idx] = acc;
}

// A = states @ W_inf   (block: 4 rows x 64 cols)
__global__ void k_matA(const float* S, const float* W, float* A_) {
    __shared__ float Wl[64 * 64];
    __shared__ float Sl[4][64];
    int t = threadIdx.x;
    for (int k = t; k < 4096; k += 256) Wl[k] = W[k];
    int row0 = blockIdx.x * 4;
    { int r = t >> 6, c = t & 63; Sl[r][c] = S[(row0 + r) * 64 + c]; }
    __syncthreads();
    int r = t >> 6, c = t & 63;
    float acc = 0.f;
    #pragma unroll
    for (int k = 0; k < 64; k++) acc += Sl[r][k] * Wl[k * 64 + c];
    A_[(row0 + r) * 64 + c] = acc;
}

// one wave per agent; lane = feature dim
__global__ void k_neighbors(const int* pos, const int* roles, const float* S, const float* A_,
                            const int* cellcnt, const int* bucket,
                            float* outsum, float* insum, int* nnbr, int* massn, int* fin, int* tgtb) {
    int wid = threadIdx.x >> 6;
    int lane = threadIdx.x & 63;
    int i = blockIdx.x * (blockDim.x >> 6) + wid;
    if (i >= N) return;
    int xi = pos[2 * i], yi = pos[2 * i + 1];
    float a_l = A_[i * 64 + lane];
    float s_l = S[i * 64 + lane];
    float osum = 0.f, isum = 0.f;
    int nn = 0, mn = 0, fn = 0;
    int bestkey = 0x7FFFFFFF;
    for (int oy = -5; oy <= 5; oy++) {
        int cy = yi + oy;
        if ((unsigned)cy >= G) continue;
        for (int ox = -5; ox <= 5; ox++) {
            int d2 = ox * ox + oy * oy;
            if (d2 > 25) continue;
            int cx = xi + ox;
            if ((unsigned)cx >= G) continue;
            int c = cy * G + cx;
            int cnt = cellcnt[c];
            for (int s = 0; s < cnt; s++) {
                int j = bucket[c * CAP + s];
                if (j == i) continue;
                int rj = roles[j];
                nn++; mn += (rj == 0); fn += (rj == 1);
                if (rj == 1) { int key = d2 * 8192 + j; bestkey = min(bestkey, key); }
                float po = a_l * S[j * 64 + lane];
                float pi = A_[j * 64 + lane] * s_l;
                #pragma unroll
                for (int m = 32; m >= 1; m >>= 1) {
                    po += __shfl_xor(po, m, 64);
                    pi += __shfl_xor(pi, m, 64);
                }
                osum += tanhf(po);
                isum += tanhf(pi);
            }
        }
    }
    if (lane == 0) {
        outsum[i] = osum; insum[i] = isum;
        nnbr[i] = nn; massn[i] = mn; fin[i] = fn;
        tgtb[i] = (bestkey == 0x7FFFFFFF) ? 0 : (bestkey & 8191);
    }
}

__global__ void k_final(const int* pos, const int* roles, const float* energies, const float* field,
                        const float* outsum, const float* insum,
                        const int* nnbr, const int* massn, const int* fin, const int* tgtb,
                        float* pot, float* out_e, float* out_roles, float* out_pos) {
    int i = blockIdx.x * blockDim.x + threadIdx.x;
    if (i >= N) return;
    int x = pos[2 * i], y = pos[2 * i + 1];
    float f = field[y * G + x];
    float gx = (x == 0)     ? field[y * G + 1] - field[y * G + 0]
             : (x == G - 1) ? field[y * G + G - 1] - field[y * G + G - 2]
                            : 0.5f * (field[y * G + x + 1] - field[y * G + x - 1]);
    float gy = (y == 0)     ? field[G + x] - field[x]
             : (y == G - 1) ? field[(G - 1) * G + x] - field[(G - 2) * G + x]
                            : 0.5f * (field[(y + 1) * G + x] - field[(y - 1) * G + x]);
    pot[i] = f;
    int nn = nnbr[i];
    bool has = nn > 0;
    float denom = (float)max(nn, 1);
    float net = has ? (outsum[i] / denom - insum[i] / denom) : 0.f;
    int role = roles[i];
    float e = energies[i];
    int mn = massn[i], fn = fin[i];
    float e_fi = e + 0.02f * (float)mn;
    float e_other = e * 0.995f + 0.05f * fmaxf(f, 0.f) + ((mn >= 3) ? 0.02f : 0.f);
    float new_e = ((role == 1) ? e_fi : e_other) + 0.02f * fmaxf(net, 0.f);
    new_e = fminf(fmaxf(new_e, 0.f), 1.f);
    float score = net + 0.5f;
    int r0 = ((new_e > 0.7f) && (mn >= 2) && ((fn == 0) || (score > 0.2f))) ? 1 : 0;
    int r1 = ((mn < 1) || (new_e < 0.2f) || (score < -0.3f)) ? 0 : 1;
    int r2 = ((fn > 0) && (net > 0.5f)) ? 1 : ((new_e < 0.2f) ? 0 : 2);
    int nr = (role == 0) ? r0 : (role == 1) ? r1 : r2;
    bool move_mass = (nr == 0) && ((fabsf(gx) > 0.01f) || (fabsf(gy) > 0.01f));
    int dxm = (gx > 0.f) ? 1 : ((gx < 0.f) ? -1 : 0);
    int dym = (gy > 0.f) ? 1 : ((gy < 0.f) ? -1 : 0);
    int tj = tgtb[i];
    int tx = pos[2 * tj], ty = pos[2 * tj + 1];
    int dxc = (tx > x) ? 1 : ((tx < x) ? -1 : 0);
    int dyc = (ty > y) ? 1 : ((ty < y) ? -1 : 0);
    bool move_c = (nr == 2) && (fn > 0);
    int dx = move_mass ? dxm : (move_c ? dxc : 0);
    int dy = move_mass ? dym : (move_c ? dyc : 0);
    int nx = min(max(x + dx, 0), G - 1);
    int ny = min(max(y + dy, 0), G - 1);
    out_e[i] = new_e;
    out_roles[i] = (float)nr;
    out_pos[2 * i] = (float)nx;
    out_pos[2 * i + 1] = (float)ny;
}

// h = tanh(v @ W1 + b1), v = [states + 0.1*tanh(states@W_self), potential]
#define MLP1_A 8
__global__ void k_mlp1(const float* S, const float* Wself, const float* W1, const float* b1,
                       const float* pot, float* hbuf) {
    __shared__ float Ws[4096];      // 16 KB
    __shared__ float W1l[65 * 128]; // 33.3 KB
    __shared__ float Sl[MLP1_A][64];
    __shared__ float v[MLP1_A][65];
    int t = threadIdx.x;
    for (int k = t; k < 4096; k += 256) Ws[k] = Wself[k];
    for (int k = t; k < 65 * 128; k += 256) W1l[k] = W1[k];
    int a0 = blockIdx.x * MLP1_A;
    for (int k = t; k < MLP1_A * 64; k += 256) Sl[k >> 6][k & 63] = S[a0 * 64 + k];
    __syncthreads();
    for (int e = t; e < MLP1_A * 65; e += 256) {
        int a = e / 65, k = e % 65;
        float val;
        if (k == 64) val = pot[a0 + a];
        else {
            float acc = 0.f;
            #pragma unroll
            for (int kk = 0; kk < 64; kk++) acc += Sl[a][kk] * Ws[kk * 64 + k];
            val = Sl[a][k] + 0.1f * tanhf(acc);
        }
        v[a][k] = val;
    }
    __syncthreads();
    #pragma unroll
    for (int aa = 0; aa < MLP1_A / 2; aa++) {
        int a = aa * 2 + (t >> 7), h = t & 127;
        float acc = b1[h];
        #pragma unroll
        for (int k = 0; k < 65; k++) acc += v[a][k] * W1l[k * 128 + h];
        hbuf[(a0 + a) * 128 + h] = tanhf(acc);
    }
}

// new_states = has ? (h @ W2 + b2 + 0.3*s) : s
#define MLP2_A 16
__global__ void k_mlp2(const float* hbuf, const float* W2, const float* b2, const float* S,
                       const int* nnbr, float* out_states) {
    __shared__ float W2l[128 * 64]; // 32 KB
    __shared__ float hl[MLP2_A][128];
    int t = threadIdx.x;
    for (int k = t; k < 8192; k += 256) W2l[k] = W2[k];
    int a0 = blockIdx.x * MLP2_A;
    for (int k = t; k < MLP2_A * 128; k += 256) hl[k >> 7][k & 127] = hbuf[a0 * 128 + k];
    __syncthreads();
    #pragma unroll
    for (int aa = 0; aa < MLP2_A / 4; aa++) {
        int a = aa * 4 + (t >> 6), d = t & 63;
        int i = a0 + a;
        float acc = b2[d];
        #pragma unroll
        for (int k = 0; k < 128; k++) acc += hl[a][k] * W2l[k * 64 + d];
        bool has = nnbr[i] > 0;
        float s = S[i * 64 + d];
        out_states[i * 64 + d] = has ? (acc + 0.3f * s) : s;
    }
}

extern "C" void kernel_launch(void* const* d_in, const int* in_sizes, int n_in,
                              void* d_out, int out_size, void* d_ws, size_t ws_size,
                              hipStream_t stream) {
    const int*   positions = (const int*)d_in[0];
    const float* states    = (const float*)d_in[1];
    const int*   roles     = (const int*)d_in[2];
    const float* energies  = (const float*)d_in[3];
    const float* W_inf     = (const float*)d_in[4];
    const float* W_self    = (const float*)d_in[5];
    const float* W1        = (const float*)d_in[6];
    const float* b1        = (const float*)d_in[7];
    const float* W2        = (const float*)d_in[8];
    const float* b2        = (const float*)d_in[9];

    float* wsf = (float*)d_ws;
    int*   wsi = (int*)d_ws;

    float* eg      = wsf + OFF_EGRID;
    float* rg      = wsf + OFF_RGRID;
    float* tmp     = wsf + OFF_TMP;
    float* field   = wsf + OFF_FIELD;
    float* A_      = wsf + OFF_A;
    float* hbuf    = wsf + OFF_HBUF;
    float* pot     = wsf + OFF_POT;
    float* outsum  = wsf + OFF_OUTSUM;
    float* insum   = wsf + OFF_INSUM;
    int*   nnbr    = wsi + OFF_NNBR;
    int*   massn   = wsi + OFF_MASSN;
    int*   fin     = wsi + OFF_FIN;
    int*   tgtb    = wsi + OFF_TGT;
    int*   cellcnt = wsi + OFF_CELLCNT;
    int*   bucket  = wsi + OFF_BUCKET;

    float* out_states = (float*)d_out;                 // N*D
    float* out_e      = out_states + N * D;            // N
    float* out_roles  = out_e + N;                     // N
    float* out_pos    = out_roles + N;                 // N*2

    k_zero<<<G * G / 256, 256, 0, stream>>>(eg, rg, cellcnt);
    k_scatter<<<N / 256, 256, 0, stream>>>(positions, roles, energies, eg, rg, cellcnt, bucket);
    k_sortbuckets<<<G * G / 256, 256, 0, stream>>>(cellcnt, bucket);
    k_blurV<<<G * G / 256, 256, 0, stream>>>(eg, rg, tmp);
    k_blurH<<<G * G / 256, 256, 0, stream>>>(tmp, field);
    k_matA<<<N / 4, 256, 0, stream>>>(states, W_inf, A_);
    k_neighbors<<<N / 4, 256, 0, stream>>>(positions, roles, states, A_, cellcnt, bucket,
                                           outsum, insum, nnbr, massn, fin, tgtb);
    k_final<<<N / 256, 256, 0, stream>>>(positions, roles, energies, field, outsum, insum,
                                         nnbr, massn, fin, tgtb, pot, out_e, out_roles, out_pos);
    k_mlp1<<<N / MLP1_A, 256, 0, stream>>>(states, W_self, W1, b1, pot, hbuf);
    k_mlp2<<<N / MLP2_A, 256, 0, stream>>>(hbuf, W2, b2, states, nnbr, out_states);
}

// Round 2
// 125.466 us; speedup vs baseline: 1.1203x; 1.1203x over previous
//
#include <hip/hip_runtime.h>

#define N 8192
#define G 256
#define D 64
#define H 128
#define CAP 8

// ---- workspace word offsets ----
#define OFF_EGRID   0
#define OFF_RGRID   65536
#define OFF_TMP     131072
#define OFF_FIELD   196608
#define OFF_A       262144     // 8192*64
#define OFF_HBUF    786432     // 8192*128
#define OFF_OUTSUM  1843200
#define OFF_INSUM   1851392
#define OFF_NNBR    1859584
#define OFF_MASSN   1867776
#define OFF_FIN     1875968
#define OFF_TGT     1884160
#define OFF_CELLCNT 1892352
#define OFF_BUCKET  1957888    // 65536*CAP -> end 2482176 words (~9.5 MB)

__global__ void k_zero(float* eg, float* rg, int* cellcnt) {
    int i = blockIdx.x * blockDim.x + threadIdx.x;
    if (i < G * G) { eg[i] = 0.f; rg[i] = 0.f; cellcnt[i] = 0; }
}

__global__ void k_scatter(const int* pos, const int* roles, const float* energies,
                          float* eg, float* rg, int* cellcnt, int* bucket) {
    int i = blockIdx.x * blockDim.x + threadIdx.x;
    if (i >= N) return;
    int x = pos[2 * i], y = pos[2 * i + 1];
    int c = y * G + x;
    atomicMax((int*)&eg[c], __float_as_int(energies[i]));          // non-negative floats
    atomicMax((int*)&rg[c], __float_as_int((float)roles[i]));
    int slot = atomicAdd(&cellcnt[c], 1);
    if (slot < CAP) bucket[c * CAP + slot] = i;
}

__device__ __forceinline__ void gauss_weights(float* k) {
    float s = 0.f;
    #pragma unroll
    for (int m = 0; m < 15; m++) { float xx = (float)m - 7.f; k[m] = expf(-(xx * xx) / 8.f); s += k[m]; }
    #pragma unroll
    for (int m = 0; m < 15; m++) k[m] /= s;
}

// fused: sort buckets (determinism) + vertical blur — both indexed by cell
__global__ void k_prep(int* cellcnt, int* bucket, const float* eg, const float* rg, float* tmp) {
    int idx = blockIdx.x * blockDim.x + threadIdx.x;
    if (idx >= G * G) return;
    int n = cellcnt[idx]; if (n > CAP) n = CAP;
    cellcnt[idx] = n;
    for (int a = 1; a < n; a++) {
        int v = bucket[idx * CAP + a];
        int b = a - 1;
        while (b >= 0 && bucket[idx * CAP + b] > v) { bucket[idx * CAP + b + 1] = bucket[idx * CAP + b]; b--; }
        bucket[idx * CAP + b + 1] = v;
    }
    int x = idx & (G - 1), y = idx >> 8;
    float k[15]; gauss_weights(k);
    float acc = 0.f;
    #pragma unroll
    for (int m = 0; m < 15; m++) {
        int yy = y + m - 7;
        if ((unsigned)yy < G) {
            float img = eg[yy * G + x] + 0.5f * rg[yy * G + x];
            acc += img * k[m];
        }
    }
    tmp[idx] = acc;
}

__global__ void k_blurH(const float* tmp, float* field) {
    int idx = blockIdx.x * blockDim.x + threadIdx.x;
    if (idx >= G * G) return;
    int x = idx & (G - 1), y = idx >> 8;
    float k[15]; gauss_weights(k);
    float acc = 0.f;
    #pragma unroll
    for (int m = 0; m < 15; m++) {
        int xx = x + m - 7;
        if ((unsigned)xx < G) acc += tmp[y * G + xx] * k[m];
    }
    field[idx] = acc;
}

// A = states @ W_inf   (block: 16 rows x 64 cols, each thread 4 outputs)
__global__ void k_matA(const float* S, const float* W, float* A_) {
    __shared__ float Wl[64 * 64];
    __shared__ float Sl[16][64];
    int t = threadIdx.x;
    for (int k = t; k < 4096; k += 256) Wl[k] = W[k];
    int row0 = blockIdx.x * 16;
    for (int k = t; k < 1024; k += 256) Sl[k >> 6][k & 63] = S[row0 * 64 + k];
    __syncthreads();
    int c = t & 63, r0 = (t >> 6) * 4;
    #pragma unroll
    for (int rr = 0; rr < 4; rr++) {
        float acc = 0.f;
        #pragma unroll
        for (int k = 0; k < 64; k++) acc += Sl[r0 + rr][k] * Wl[k * 64 + c];
        A_[(row0 + r0 + rr) * 64 + c] = acc;
    }
}

__device__ __forceinline__ float fast_tanh(float x) {
    float t = __expf(2.f * x);
    return 1.f - 2.f / (t + 1.f);   // correct limits at +-inf
}

// map k in [0,81) to (ox,oy) with ox^2+oy^2 <= 25, row-major by oy
__device__ __forceinline__ void cell_of(int k, int& ox, int& oy, int& d2) {
    const int w[11] = {1, 7, 9, 9, 9, 11, 9, 9, 9, 7, 1};
    int acc = 0; ox = 0; oy = 0;
    #pragma unroll
    for (int r = 0; r < 11; r++) {
        bool in = (k >= acc) && (k < acc + w[r]);
        if (in) { oy = r - 5; ox = k - acc - (w[r] >> 1); }
        acc += w[r];
    }
    d2 = ox * ox + oy * oy;
}

#define NB_WAVES 4
__global__ __launch_bounds__(256) void k_neighbors(
        const int* pos, const int* roles, const float* S, const float* A_,
        const int* cellcnt, const int* bucket,
        float* outsum, float* insum, int* nnbr, int* massn, int* fin, int* tgtb) {
    __shared__ int   lds_list[NB_WAVES][656];
    __shared__ float lds_si[NB_WAVES][64];
    __shared__ float lds_ai[NB_WAVES][64];
    int wid = threadIdx.x >> 6, lane = threadIdx.x & 63;
    int i = blockIdx.x * NB_WAVES + wid;
    int xi = pos[2 * i], yi = pos[2 * i + 1];
    lds_si[wid][lane] = S[i * 64 + lane];
    lds_ai[wid][lane] = A_[i * 64 + lane];

    // ---- phase 1: lane-parallel scan of the 81 candidate cells ----
    int cnt0 = 0, cnt1 = 0, c0 = 0, c1 = 0, d2_0 = 0, d2_1 = 0;
    {
        int ox, oy, d2; cell_of(lane, ox, oy, d2);
        int cx = xi + ox, cy = yi + oy;
        if ((unsigned)cx < G && (unsigned)cy < G) { c0 = cy * G + cx; d2_0 = d2; cnt0 = cellcnt[c0]; }
    }
    if (lane < 17) {
        int ox, oy, d2; cell_of(64 + lane, ox, oy, d2);
        int cx = xi + ox, cy = yi + oy;
        if ((unsigned)cx < G && (unsigned)cy < G) { c1 = cy * G + cx; d2_1 = d2; cnt1 = cellcnt[c1]; }
    }
    int x0 = cnt0;
    #pragma unroll
    for (int d = 1; d < 64; d <<= 1) { int y = __shfl_up(x0, d, 64); if (lane >= d) x0 += y; }
    int excl0 = x0 - cnt0, total0 = __shfl(x0, 63, 64);
    int x1 = cnt1;
    #pragma unroll
    for (int d = 1; d < 64; d <<= 1) { int y = __shfl_up(x1, d, 64); if (lane >= d) x1 += y; }
    int excl1 = x1 - cnt1, total1 = __shfl(x1, 63, 64);
    int nn_raw = total0 + total1;
    for (int s = 0; s < cnt0; s++) {
        int j = bucket[c0 * CAP + s];
        lds_list[wid][excl0 + s] = (d2_0 << 13) | j;
    }
    for (int s = 0; s < cnt1; s++) {
        int j = bucket[c1 * CAP + s];
        lds_list[wid][total0 + excl1 + s] = (d2_1 << 13) | j;
    }
    __syncthreads();

    // ---- phase 2: lane = neighbor entry ----
    float osum_p = 0.f, isum_p = 0.f;
    int nn = 0, mn = 0, fn = 0, bestkey = 0x7FFFFFFF;
    const float4* S4 = (const float4*)S;
    const float4* A4 = (const float4*)A_;
    const float4* si4 = (const float4*)lds_si[wid];
    const float4* ai4 = (const float4*)lds_ai[wid];
    for (int base = 0; base < nn_raw; base += 64) {
        int e = base + lane;
        bool inrange = e < nn_raw;
        int key = inrange ? lds_list[wid][e] : 0;
        int j = key & 8191;
        bool valid = inrange && (j != i);
        int rj = valid ? roles[j] : -1;
        nn += __popcll(__ballot(valid));
        mn += __popcll(__ballot(rj == 0));
        fn += __popcll(__ballot(rj == 1));
        int cand = (rj == 1) ? key : 0x7FFFFFFF;
        #pragma unroll
        for (int m = 32; m >= 1; m >>= 1) cand = min(cand, __shfl_xor(cand, m, 64));
        bestkey = min(bestkey, cand);
        if (valid) {
            const float4* srow = S4 + j * 16;
            const float4* arow = A4 + j * 16;
            float po0 = 0.f, po1 = 0.f, pi0 = 0.f, pi1 = 0.f;
            #pragma unroll
            for (int k = 0; k < 16; k += 2) {
                float4 sj = srow[k],     aj = arow[k];
                float4 av = ai4[k],      sv = si4[k];
                po0 += sj.x * av.x + sj.y * av.y + sj.z * av.z + sj.w * av.w;
                pi0 += aj.x * sv.x + aj.y * sv.y + aj.z * sv.z + aj.w * sv.w;
                float4 sj1 = srow[k + 1], aj1 = arow[k + 1];
                float4 av1 = ai4[k + 1],  sv1 = si4[k + 1];
                po1 += sj1.x * av1.x + sj1.y * av1.y + sj1.z * av1.z + sj1.w * av1.w;
                pi1 += aj1.x * sv1.x + aj1.y * sv1.y + aj1.z * sv1.z + aj1.w * sv1.w;
            }
            osum_p += fast_tanh(po0 + po1);
            isum_p += fast_tanh(pi0 + pi1);
        }
    }
    #pragma unroll
    for (int m = 32; m >= 1; m >>= 1) {
        osum_p += __shfl_xor(osum_p, m, 64);
        isum_p += __shfl_xor(isum_p, m, 64);
    }
    if (lane == 0) {
        outsum[i] = osum_p; insum[i] = isum_p;
        nnbr[i] = nn; massn[i] = mn; fin[i] = fn;
        tgtb[i] = (bestkey == 0x7FFFFFFF) ? 0 : (bestkey & 8191);
    }
}

__global__ void k_final(const int* pos, const int* roles, const float* energies, const float* field,
                        const float* outsum, const float* insum,
                        const int* nnbr, const int* massn, const int* fin, const int* tgtb,
                        float* out_e, float* out_roles, float* out_pos) {
    int i = blockIdx.x * blockDim.x + threadIdx.x;
    if (i >= N) return;
    int x = pos[2 * i], y = pos[2 * i + 1];
    float f = field[y * G + x];
    float gx = (x == 0)     ? field[y * G + 1] - field[y * G + 0]
             : (x == G - 1) ? field[y * G + G - 1] - field[y * G + G - 2]
                            : 0.5f * (field[y * G + x + 1] - field[y * G + x - 1]);
    float gy = (y == 0)     ? field[G + x] - field[x]
             : (y == G - 1) ? field[(G - 1) * G + x] - field[(G - 2) * G + x]
                            : 0.5f * (field[(y + 1) * G + x] - field[(y - 1) * G + x]);
    int nn = nnbr[i];
    bool has = nn > 0;
    float denom = (float)max(nn, 1);
    float net = has ? (outsum[i] / denom - insum[i] / denom) : 0.f;
    int role = roles[i];
    float e = energies[i];
    int mn = massn[i], fn = fin[i];
    float e_fi = e + 0.02f * (float)mn;
    float e_other = e * 0.995f + 0.05f * fmaxf(f, 0.f) + ((mn >= 3) ? 0.02f : 0.f);
    float new_e = ((role == 1) ? e_fi : e_other) + 0.02f * fmaxf(net, 0.f);
    new_e = fminf(fmaxf(new_e, 0.f), 1.f);
    float score = net + 0.5f;
    int r0 = ((new_e > 0.7f) && (mn >= 2) && ((fn == 0) || (score > 0.2f))) ? 1 : 0;
    int r1 = ((mn < 1) || (new_e < 0.2f) || (score < -0.3f)) ? 0 : 1;
    int r2 = ((fn > 0) && (net > 0.5f)) ? 1 : ((new_e < 0.2f) ? 0 : 2);
    int nr = (role == 0) ? r0 : (role == 1) ? r1 : r2;
    bool move_mass = (nr == 0) && ((fabsf(gx) > 0.01f) || (fabsf(gy) > 0.01f));
    int dxm = (gx > 0.f) ? 1 : ((gx < 0.f) ? -1 : 0);
    int dym = (gy > 0.f) ? 1 : ((gy < 0.f) ? -1 : 0);
    int tj = tgtb[i];
    int tx = pos[2 * tj], ty = pos[2 * tj + 1];
    int dxc = (tx > x) ? 1 : ((tx < x) ? -1 : 0);
    int dyc = (ty > y) ? 1 : ((ty < y) ? -1 : 0);
    bool move_c = (nr == 2) && (fn > 0);
    int dx = move_mass ? dxm : (move_c ? dxc : 0);
    int dy = move_mass ? dym : (move_c ? dyc : 0);
    int nx = min(max(x + dx, 0), G - 1);
    int ny = min(max(y + dy, 0), G - 1);
    out_e[i] = new_e;
    out_roles[i] = (float)nr;
    out_pos[2 * i] = (float)nx;
    out_pos[2 * i + 1] = (float)ny;
}

// h = tanh(v @ W1 + b1), v = [states + 0.1*tanh(states@W_self), field[pos]]
#define MLP1_A 16
__global__ void k_mlp1(const float* S, const float* Wself, const float* W1, const float* b1,
                       const int* pos, const float* field, float* hbuf) {
    __shared__ float Ws[4096];       // 16 KB
    __shared__ float W1l[65 * 128];  // 33.3 KB
    __shared__ float Sl[MLP1_A][64]; // 4 KB
    __shared__ float v[MLP1_A][65];  // 4.2 KB
    int t = threadIdx.x;
    for (int k = t; k < 4096; k += 256) Ws[k] = Wself[k];
    for (int k = t; k < 65 * 128; k += 256) W1l[k] = W1[k];
    int a0 = blockIdx.x * MLP1_A;
    for (int k = t; k < MLP1_A * 64; k += 256) Sl[k >> 6][k & 63] = S[a0 * 64 + k];
    __syncthreads();
    for (int e = t; e < MLP1_A * 65; e += 256) {
        int a = e / 65, k = e % 65;
        float val;
        if (k == 64) {
            int ai = a0 + a;
            int x = pos[2 * ai], y = pos[2 * ai + 1];
            val = field[y * G + x];
        } else {
            float acc = 0.f;
            #pragma unroll
            for (int kk = 0; kk < 64; kk++) acc += Sl[a][kk] * Ws[kk * 64 + k];
            val = Sl[a][k] + 0.1f * tanhf(acc);
        }
        v[a][k] = val;
    }
    __syncthreads();
    #pragma unroll
    for (int aa = 0; aa < MLP1_A / 2; aa++) {
        int a = aa * 2 + (t >> 7), h = t & 127;
        float acc = b1[h];
        #pragma unroll
        for (int k = 0; k < 65; k++) acc += v[a][k] * W1l[k * 128 + h];
        hbuf[(a0 + a) * 128 + h] = tanhf(acc);
    }
}

// new_states = has ? (h @ W2 + b2 + 0.3*s) : s
#define MLP2_A 32
__global__ void k_mlp2(const float* hbuf, const float* W2, const float* b2, const float* S,
                       const int* nnbr, float* out_states) {
    __shared__ float W2l[128 * 64];   // 32 KB
    __shared__ float hl[MLP2_A][128]; // 16 KB
    int t = threadIdx.x;
    for (int k = t; k < 8192; k += 256) W2l[k] = W2[k];
    int a0 = blockIdx.x * MLP2_A;
    for (int k = t; k < MLP2_A * 128; k += 256) hl[k >> 7][k & 127] = hbuf[a0 * 128 + k];
    __syncthreads();
    #pragma unroll
    for (int aa = 0; aa < MLP2_A / 4; aa++) {
        int a = aa * 4 + (t >> 6), d = t & 63;
        int i = a0 + a;
        float acc = b2[d];
        #pragma unroll
        for (int k = 0; k < 128; k++) acc += hl[a][k] * W2l[k * 64 + d];
        bool has = nnbr[i] > 0;
        float s = S[i * 64 + d];
        out_states[i * 64 + d] = has ? (acc + 0.3f * s) : s;
    }
}

extern "C" void kernel_launch(void* const* d_in, const int* in_sizes, int n_in,
                              void* d_out, int out_size, void* d_ws, size_t ws_size,
                              hipStream_t stream) {
    const int*   positions = (const int*)d_in[0];
    const float* states    = (const float*)d_in[1];
    const int*   roles     = (const int*)d_in[2];
    const float* energies  = (const float*)d_in[3];
    const float* W_inf     = (const float*)d_in[4];
    const float* W_self    = (const float*)d_in[5];
    const float* W1        = (const float*)d_in[6];
    const float* b1        = (const float*)d_in[7];
    const float* W2        = (const float*)d_in[8];
    const float* b2        = (const float*)d_in[9];

    float* wsf = (float*)d_ws;
    int*   wsi = (int*)d_ws;

    float* eg      = wsf + OFF_EGRID;
    float* rg      = wsf + OFF_RGRID;
    float* tmp     = wsf + OFF_TMP;
    float* field   = wsf + OFF_FIELD;
    float* A_      = wsf + OFF_A;
    float* hbuf    = wsf + OFF_HBUF;
    float* outsum  = wsf + OFF_OUTSUM;
    float* insum   = wsf + OFF_INSUM;
    int*   nnbr    = wsi + OFF_NNBR;
    int*   massn   = wsi + OFF_MASSN;
    int*   fin     = wsi + OFF_FIN;
    int*   tgtb    = wsi + OFF_TGT;
    int*   cellcnt = wsi + OFF_CELLCNT;
    int*   bucket  = wsi + OFF_BUCKET;

    float* out_states = (float*)d_out;                 // N*D
    float* out_e      = out_states + N * D;            // N
    float* out_roles  = out_e + N;                     // N
    float* out_pos    = out_roles + N;                 // N*2

    k_zero<<<G * G / 256, 256, 0, stream>>>(eg, rg, cellcnt);
    k_scatter<<<N / 256, 256, 0, stream>>>(positions, roles, energies, eg, rg, cellcnt, bucket);
    k_prep<<<G * G / 256, 256, 0, stream>>>(cellcnt, bucket, eg, rg, tmp);
    k_blurH<<<G * G / 256, 256, 0, stream>>>(tmp, field);
    k_matA<<<N / 16, 256, 0, stream>>>(states, W_inf, A_);
    k_neighbors<<<N / NB_WAVES, 256, 0, stream>>>(positions, roles, states, A_, cellcnt, bucket,
                                                  outsum, insum, nnbr, massn, fin, tgtb);
    k_final<<<N / 256, 256, 0, stream>>>(positions, roles, energies, field, outsum, insum,
                                         nnbr, massn, fin, tgtb, out_e, out_roles, out_pos);
    k_mlp1<<<N / MLP1_A, 256, 0, stream>>>(states, W_self, W1, b1, positions, field, hbuf);
    k_mlp2<<<N / MLP2_A, 256, 0, stream>>>(hbuf, W2, b2, states, nnbr, out_states);
}

// Round 6
// 101.567 us; speedup vs baseline: 1.3840x; 1.2353x over previous
//
#include <hip/hip_runtime.h>

#define N 8192
#define G 256
#define D 64
#define H 128
#define CAP 8

// ---- workspace word offsets ----
#define OFF_EGRID   0
#define OFF_RGRID   65536
#define OFF_TMP     131072
#define OFF_FIELD   196608
#define OFF_A       262144     // 8192*64
#define OFF_HBUF    786432     // 8192*128
#define OFF_OUTSUM  1843200
#define OFF_INSUM   1851392
#define OFF_NNBR    1859584
#define OFF_MASSN   1867776
#define OFF_FIN     1875968
#define OFF_TGT     1884160
#define OFF_CELLCNT 1892352
#define OFF_BUCKET  1957888    // 65536*CAP -> end 2482176 words (~9.5 MB)

__global__ void k_zero(float* eg, float* rg, int* cellcnt) {
    int i = blockIdx.x * blockDim.x + threadIdx.x;
    if (i < G * G) { eg[i] = 0.f; rg[i] = 0.f; cellcnt[i] = 0; }
}

__global__ void k_scatter(const int* pos, const int* roles, const float* energies,
                          float* eg, float* rg, int* cellcnt, int* bucket) {
    int i = blockIdx.x * blockDim.x + threadIdx.x;
    if (i >= N) return;
    int x = pos[2 * i], y = pos[2 * i + 1];
    int c = y * G + x;
    atomicMax((int*)&eg[c], __float_as_int(energies[i]));          // non-negative floats
    atomicMax((int*)&rg[c], __float_as_int((float)roles[i]));
    int slot = atomicAdd(&cellcnt[c], 1);
    if (slot < CAP) bucket[c * CAP + slot] = i;
}

__device__ __forceinline__ void gauss_weights(float* k) {
    float s = 0.f;
    #pragma unroll
    for (int m = 0; m < 15; m++) { float xx = (float)m - 7.f; k[m] = expf(-(xx * xx) / 8.f); s += k[m]; }
    #pragma unroll
    for (int m = 0; m < 15; m++) k[m] /= s;
}

// fused: sort buckets (determinism) + vertical blur — both indexed by cell
__global__ void k_prep(int* cellcnt, int* bucket, const float* eg, const float* rg, float* tmp) {
    int idx = blockIdx.x * blockDim.x + threadIdx.x;
    if (idx >= G * G) return;
    int n = cellcnt[idx]; if (n > CAP) n = CAP;
    cellcnt[idx] = n;
    for (int a = 1; a < n; a++) {
        int v = bucket[idx * CAP + a];
        int b = a - 1;
        while (b >= 0 && bucket[idx * CAP + b] > v) { bucket[idx * CAP + b + 1] = bucket[idx * CAP + b]; b--; }
        bucket[idx * CAP + b + 1] = v;
    }
    int x = idx & (G - 1), y = idx >> 8;
    float k[15]; gauss_weights(k);
    float acc = 0.f;
    #pragma unroll
    for (int m = 0; m < 15; m++) {
        int yy = y + m - 7;
        if ((unsigned)yy < G) {
            float img = eg[yy * G + x] + 0.5f * rg[yy * G + x];
            acc += img * k[m];
        }
    }
    tmp[idx] = acc;
}

// heterogeneous fusion: blocks [0,512) do A = S @ W_inf (16 rows each);
// blocks [512,768) do the horizontal blur pass.
__global__ void k_blurH_matA(const float* tmp, float* field, const float* S, const float* W, float* A_) {
    __shared__ float sh[4096 + 16 * 64];
    int t = threadIdx.x;
    if (blockIdx.x < 512) {
        float* Wl = sh;
        float* Sl = sh + 4096;
        const float4* W4 = (const float4*)W;
        float4* Wl4 = (float4*)Wl;
        for (int k = t; k < 1024; k += 256) Wl4[k] = W4[k];
        int row0 = blockIdx.x * 16;
        const float4* S4 = (const float4*)(S + row0 * 64);
        float4* Sl4 = (float4*)Sl;
        for (int k = t; k < 256; k += 256) Sl4[k] = S4[k];
        __syncthreads();
        int c = t & 63, r0 = (t >> 6) * 4;
        #pragma unroll
        for (int rr = 0; rr < 4; rr++) {
            float acc = 0.f;
            #pragma unroll
            for (int k = 0; k < 64; k++) acc += Sl[(r0 + rr) * 64 + k] * Wl[k * 64 + c];
            A_[(row0 + r0 + rr) * 64 + c] = acc;
        }
    } else {
        int idx = (blockIdx.x - 512) * 256 + t;
        int x = idx & (G - 1), y = idx >> 8;
        float k[15]; gauss_weights(k);
        float acc = 0.f;
        #pragma unroll
        for (int m = 0; m < 15; m++) {
            int xx = x + m - 7;
            if ((unsigned)xx < G) acc += tmp[y * G + xx] * k[m];
        }
        field[idx] = acc;
    }
}

__device__ __forceinline__ float fast_tanh(float x) {
    float t = __expf(2.f * x);
    return 1.f - 2.f / (t + 1.f);   // correct limits at +-inf
}

// map k in [0,81) to (ox,oy) with ox^2+oy^2 <= 25, row-major by oy
__device__ __forceinline__ void cell_of(int k, int& ox, int& oy, int& d2) {
    const int w[11] = {1, 7, 9, 9, 9, 11, 9, 9, 9, 7, 1};
    int acc = 0; ox = 0; oy = 0;
    #pragma unroll
    for (int r = 0; r < 11; r++) {
        bool in = (k >= acc) && (k < acc + w[r]);
        if (in) { oy = r - 5; ox = k - acc - (w[r] >> 1); }
        acc += w[r];
    }
    d2 = ox * ox + oy * oy;
}

#define NB_WAVES 4
__global__ __launch_bounds__(256) void k_neighbors(
        const int* pos, const int* roles, const float* S, const float* A_,
        const int* cellcnt, const int* bucket,
        float* outsum, float* insum, int* nnbr, int* massn, int* fin, int* tgtb) {
    __shared__ int   lds_list[NB_WAVES][656];
    __shared__ float lds_si[NB_WAVES][64];
    __shared__ float lds_ai[NB_WAVES][64];
    int wid = threadIdx.x >> 6, lane = threadIdx.x & 63;
    int i = blockIdx.x * NB_WAVES + wid;
    int xi = pos[2 * i], yi = pos[2 * i + 1];
    lds_si[wid][lane] = S[i * 64 + lane];
    lds_ai[wid][lane] = A_[i * 64 + lane];

    // ---- phase 1: lane-parallel scan of the 81 candidate cells ----
    int cnt0 = 0, cnt1 = 0, c0 = 0, c1 = 0, d2_0 = 0, d2_1 = 0;
    {
        int ox, oy, d2; cell_of(lane, ox, oy, d2);
        int cx = xi + ox, cy = yi + oy;
        if ((unsigned)cx < G && (unsigned)cy < G) { c0 = cy * G + cx; d2_0 = d2; cnt0 = cellcnt[c0]; }
    }
    if (lane < 17) {
        int ox, oy, d2; cell_of(64 + lane, ox, oy, d2);
        int cx = xi + ox, cy = yi + oy;
        if ((unsigned)cx < G && (unsigned)cy < G) { c1 = cy * G + cx; d2_1 = d2; cnt1 = cellcnt[c1]; }
    }
    int x0 = cnt0;
    #pragma unroll
    for (int d = 1; d < 64; d <<= 1) { int y = __shfl_up(x0, d, 64); if (lane >= d) x0 += y; }
    int excl0 = x0 - cnt0, total0 = __shfl(x0, 63, 64);
    int x1 = cnt1;
    #pragma unroll
    for (int d = 1; d < 64; d <<= 1) { int y = __shfl_up(x1, d, 64); if (lane >= d) x1 += y; }
    int excl1 = x1 - cnt1, total1 = __shfl(x1, 63, 64);
    int nn_raw = total0 + total1;
    for (int s = 0; s < cnt0; s++) {
        int j = bucket[c0 * CAP + s];
        lds_list[wid][excl0 + s] = (d2_0 << 13) | j;
    }
    for (int s = 0; s < cnt1; s++) {
        int j = bucket[c1 * CAP + s];
        lds_list[wid][total0 + excl1 + s] = (d2_1 << 13) | j;
    }
    __syncthreads();

    // ---- phase 2: lane = neighbor entry ----
    float osum_p = 0.f, isum_p = 0.f;
    int nn = 0, mn = 0, fn = 0, bestkey = 0x7FFFFFFF;
    const float4* S4 = (const float4*)S;
    const float4* A4 = (const float4*)A_;
    const float4* si4 = (const float4*)lds_si[wid];
    const float4* ai4 = (const float4*)lds_ai[wid];
    for (int base = 0; base < nn_raw; base += 64) {
        int e = base + lane;
        bool inrange = e < nn_raw;
        int key = inrange ? lds_list[wid][e] : 0;
        int j = key & 8191;
        bool valid = inrange && (j != i);
        int rj = valid ? roles[j] : -1;
        nn += __popcll(__ballot(valid));
        mn += __popcll(__ballot(rj == 0));
        fn += __popcll(__ballot(rj == 1));
        int cand = (rj == 1) ? key : 0x7FFFFFFF;
        #pragma unroll
        for (int m = 32; m >= 1; m >>= 1) cand = min(cand, __shfl_xor(cand, m, 64));
        bestkey = min(bestkey, cand);
        if (valid) {
            const float4* srow = S4 + j * 16;
            const float4* arow = A4 + j * 16;
            float po0 = 0.f, po1 = 0.f, pi0 = 0.f, pi1 = 0.f;
            #pragma unroll
            for (int k = 0; k < 16; k += 2) {
                float4 sj = srow[k],     aj = arow[k];
                float4 av = ai4[k],      sv = si4[k];
                po0 += sj.x * av.x + sj.y * av.y + sj.z * av.z + sj.w * av.w;
                pi0 += aj.x * sv.x + aj.y * sv.y + aj.z * sv.z + aj.w * sv.w;
                float4 sj1 = srow[k + 1], aj1 = arow[k + 1];
                float4 av1 = ai4[k + 1],  sv1 = si4[k + 1];
                po1 += sj1.x * av1.x + sj1.y * av1.y + sj1.z * av1.z + sj1.w * av1.w;
                pi1 += aj1.x * sv1.x + aj1.y * sv1.y + aj1.z * sv1.z + aj1.w * sv1.w;
            }
            osum_p += fast_tanh(po0 + po1);
            isum_p += fast_tanh(pi0 + pi1);
        }
    }
    #pragma unroll
    for (int m = 32; m >= 1; m >>= 1) {
        osum_p += __shfl_xor(osum_p, m, 64);
        isum_p += __shfl_xor(isum_p, m, 64);
    }
    if (lane == 0) {
        outsum[i] = osum_p; insum[i] = isum_p;
        nnbr[i] = nn; massn[i] = mn; fin[i] = fn;
        tgtb[i] = (bestkey == 0x7FFFFFFF) ? 0 : (bestkey & 8191);
    }
}

// h = tanh(v @ W1 + b1), v = [states + 0.1*tanh(states@W_self), field[pos]]
#define MLP1_A 16
__global__ void k_mlp1(const float* S, const float* Wself, const float* W1, const float* b1,
                       const int* pos, const float* field, float* hbuf) {
    __shared__ float Ws[4096];       // 16 KB
    __shared__ float W1l[65 * 128];  // 33.3 KB
    __shared__ float Sl[MLP1_A][64]; // 4 KB
    __shared__ float v[MLP1_A][65];  // 4.2 KB
    int t = threadIdx.x;
    {
        const float4* Ws4 = (const float4*)Wself;
        float4* Wsl4 = (float4*)Ws;
        for (int k = t; k < 1024; k += 256) Wsl4[k] = Ws4[k];
        const float4* W14 = (const float4*)W1;
        float4* W1l4 = (float4*)W1l;
        for (int k = t; k < 2080; k += 256) W1l4[k] = W14[k];
    }
    int a0 = blockIdx.x * MLP1_A;
    {
        const float4* S4 = (const float4*)(S + a0 * 64);
        float4* Sl4 = (float4*)Sl;
        for (int k = t; k < MLP1_A * 16; k += 256) Sl4[k] = S4[k];
    }
    __syncthreads();
    for (int e = t; e < MLP1_A * 65; e += 256) {
        int a = e / 65, k = e % 65;
        float val;
        if (k == 64) {
            int ai = a0 + a;
            int x = pos[2 * ai], y = pos[2 * ai + 1];
            val = field[y * G + x];
        } else {
            float acc = 0.f;
            #pragma unroll
            for (int kk = 0; kk < 64; kk++) acc += Sl[a][kk] * Ws[kk * 64 + k];
            val = Sl[a][k] + 0.1f * tanhf(acc);
        }
        v[a][k] = val;
    }
    __syncthreads();
    #pragma unroll
    for (int aa = 0; aa < MLP1_A / 2; aa++) {
        int a = aa * 2 + (t >> 7), h = t & 127;
        float acc = b1[h];
        #pragma unroll
        for (int k = 0; k < 65; k++) acc += v[a][k] * W1l[k * 128 + h];
        hbuf[(a0 + a) * 128 + h] = tanhf(acc);
    }
}

// new_states = has ? (h @ W2 + b2 + 0.3*s) : s   + fused per-agent final logic
#define MLP2_A 16
__global__ void k_mlp2f(const float* hbuf, const float* W2, const float* b2, const float* S,
                        const int* pos, const int* roles, const float* energies, const float* field,
                        const float* outsum, const float* insum,
                        const int* nnbr, const int* massn, const int* fin, const int* tgtb,
                        float* out_states, float* out_e, float* out_roles, float* out_pos) {
    __shared__ float W2l[128 * 64];    // 32 KB
    __shared__ float hl[MLP2_A][128];  // 8 KB
    int t = threadIdx.x;
    {
        const float4* W24 = (const float4*)W2;
        float4* W2l4 = (float4*)W2l;
        for (int k = t; k < 2048; k += 256) W2l4[k] = W24[k];
    }
    int a0 = blockIdx.x * MLP2_A;
    {
        const float4* hb4 = (const float4*)(hbuf + a0 * 128);
        float4* hl4 = (float4*)hl;
        for (int k = t; k < MLP2_A * 32; k += 256) hl4[k] = hb4[k];
    }
    __syncthreads();
    #pragma unroll
    for (int aa = 0; aa < MLP2_A / 4; aa++) {
        int a = aa * 4 + (t >> 6), d = t & 63;
        int i = a0 + a;
        float acc = b2[d];
        #pragma unroll
        for (int k = 0; k < 128; k++) acc += hl[a][k] * W2l[k * 64 + d];
        bool has = nnbr[i] > 0;
        float s = S[i * 64 + d];
        out_states[i * 64 + d] = has ? (acc + 0.3f * s) : s;
    }
    if (t < MLP2_A) {
        int i = a0 + t;
        int x = pos[2 * i], y = pos[2 * i + 1];
        float f = field[y * G + x];
        float gx = (x == 0)     ? field[y * G + 1] - field[y * G + 0]
                 : (x == G - 1) ? field[y * G + G - 1] - field[y * G + G - 2]
                                : 0.5f * (field[y * G + x + 1] - field[y * G + x - 1]);
        float gy = (y == 0)     ? field[G + x] - field[x]
                 : (y == G - 1) ? field[(G - 1) * G + x] - field[(G - 2) * G + x]
                                : 0.5f * (field[(y + 1) * G + x] - field[(y - 1) * G + x]);
        int nn = nnbr[i];
        bool has = nn > 0;
        float denom = (float)max(nn, 1);
        float net = has ? (outsum[i] / denom - insum[i] / denom) : 0.f;
        int role = roles[i];
        float e = energies[i];
        int mn = massn[i], fn = fin[i];
        float e_fi = e + 0.02f * (float)mn;
        float e_other = e * 0.995f + 0.05f * fmaxf(f, 0.f) + ((mn >= 3) ? 0.02f : 0.f);
        float new_e = ((role == 1) ? e_fi : e_other) + 0.02f * fmaxf(net, 0.f);
        new_e = fminf(fmaxf(new_e, 0.f), 1.f);
        float score = net + 0.5f;
        int r0 = ((new_e > 0.7f) && (mn >= 2) && ((fn == 0) || (score > 0.2f))) ? 1 : 0;
        int r1 = ((mn < 1) || (new_e < 0.2f) || (score < -0.3f)) ? 0 : 1;
        int r2 = ((fn > 0) && (net > 0.5f)) ? 1 : ((new_e < 0.2f) ? 0 : 2);
        int nr = (role == 0) ? r0 : (role == 1) ? r1 : r2;
        bool move_mass = (nr == 0) && ((fabsf(gx) > 0.01f) || (fabsf(gy) > 0.01f));
        int dxm = (gx > 0.f) ? 1 : ((gx < 0.f) ? -1 : 0);
        int dym = (gy > 0.f) ? 1 : ((gy < 0.f) ? -1 : 0);
        int tj = tgtb[i];
        int tx = pos[2 * tj], ty = pos[2 * tj + 1];
        int dxc = (tx > x) ? 1 : ((tx < x) ? -1 : 0);
        int dyc = (ty > y) ? 1 : ((ty < y) ? -1 : 0);
        bool move_c = (nr == 2) && (fn > 0);
        int dx = move_mass ? dxm : (move_c ? dxc : 0);
        int dy = move_mass ? dym : (move_c ? dyc : 0);
        int nx = min(max(x + dx, 0), G - 1);
        int ny = min(max(y + dy, 0), G - 1);
        out_e[i] = new_e;
        out_roles[i] = (float)nr;
        out_pos[2 * i] = (float)nx;
        out_pos[2 * i + 1] = (float)ny;
    }
}

extern "C" void kernel_launch(void* const* d_in, const int* in_sizes, int n_in,
                              void* d_out, int out_size, void* d_ws, size_t ws_size,
                              hipStream_t stream) {
    const int*   positions = (const int*)d_in[0];
    const float* states    = (const float*)d_in[1];
    const int*   roles     = (const int*)d_in[2];
    const float* energies  = (const float*)d_in[3];
    const float* W_inf     = (const float*)d_in[4];
    const float* W_self    = (const float*)d_in[5];
    const float* W1        = (const float*)d_in[6];
    const float* b1        = (const float*)d_in[7];
    const float* W2        = (const float*)d_in[8];
    const float* b2        = (const float*)d_in[9];

    float* wsf = (float*)d_ws;
    int*   wsi = (int*)d_ws;

    float* eg      = wsf + OFF_EGRID;
    float* rg      = wsf + OFF_RGRID;
    float* tmp     = wsf + OFF_TMP;
    float* field   = wsf + OFF_FIELD;
    float* A_      = wsf + OFF_A;
    float* hbuf    = wsf + OFF_HBUF;
    float* outsum  = wsf + OFF_OUTSUM;
    float* insum   = wsf + OFF_INSUM;
    int*   nnbr    = wsi + OFF_NNBR;
    int*   massn   = wsi + OFF_MASSN;
    int*   fin     = wsi + OFF_FIN;
    int*   tgtb    = wsi + OFF_TGT;
    int*   cellcnt = wsi + OFF_CELLCNT;
    int*   bucket  = wsi + OFF_BUCKET;

    float* out_states = (float*)d_out;                 // N*D
    float* out_e      = out_states + N * D;            // N
    float* out_roles  = out_e + N;                     // N
    float* out_pos    = out_roles + N;                 // N*2

    k_zero<<<G * G / 256, 256, 0, stream>>>(eg, rg, cellcnt);
    k_scatter<<<N / 256, 256, 0, stream>>>(positions, roles, energies, eg, rg, cellcnt, bucket);
    k_prep<<<G * G / 256, 256, 0, stream>>>(cellcnt, bucket, eg, rg, tmp);
    k_blurH_matA<<<512 + 256, 256, 0, stream>>>(tmp, field, states, W_inf, A_);
    k_neighbors<<<N / NB_WAVES, 256, 0, stream>>>(positions, roles, states, A_, cellcnt, bucket,
                                                  outsum, insum, nnbr, massn, fin, tgtb);
    k_mlp1<<<N / MLP1_A, 256, 0, stream>>>(states, W_self, W1, b1, positions, field, hbuf);
    k_mlp2f<<<N / MLP2_A, 256, 0, stream>>>(hbuf, W2, b2, states,
                                            positions, roles, energies, field, outsum, insum,
                                            nnbr, massn, fin, tgtb,
                                            out_states, out_e, out_roles, out_pos);
}

// Round 7
// 83.324 us; speedup vs baseline: 1.6870x; 1.2189x over previous
//
#include <hip/hip_runtime.h>

#define N 8192
#define G 256
#define D 64
#define H 128
#define CAP 8

// ---- workspace word offsets ----
#define OFF_EGRID   0
#define OFF_RGRID   65536
#define OFF_TMP     131072
#define OFF_FIELD   196608
#define OFF_A       262144     // 8192*64
#define OFF_HBUF    786432     // 8192*128
#define OFF_OUTSUM  1843200
#define OFF_INSUM   1851392
#define OFF_NNBR    1859584
#define OFF_MASSN   1867776
#define OFF_FIN     1875968
#define OFF_TGT     1884160
#define OFF_CELLCNT 1892352
#define OFF_BUCKET  1957888    // 65536*CAP -> end 2482176 words (~9.5 MB)

__global__ void k_zero(float* eg, float* rg, int* cellcnt) {
    int i = blockIdx.x * blockDim.x + threadIdx.x;
    if (i < G * G) { eg[i] = 0.f; rg[i] = 0.f; cellcnt[i] = 0; }
}

__global__ void k_scatter(const int* pos, const int* roles, const float* energies,
                          float* eg, float* rg, int* cellcnt, int* bucket) {
    int i = blockIdx.x * blockDim.x + threadIdx.x;
    if (i >= N) return;
    int x = pos[2 * i], y = pos[2 * i + 1];
    int c = y * G + x;
    atomicMax((int*)&eg[c], __float_as_int(energies[i]));          // non-negative floats
    atomicMax((int*)&rg[c], __float_as_int((float)roles[i]));
    int slot = atomicAdd(&cellcnt[c], 1);
    if (slot < CAP) bucket[c * CAP + slot] = i;
}

__device__ __forceinline__ void gauss_weights(float* k) {
    float s = 0.f;
    #pragma unroll
    for (int m = 0; m < 15; m++) { float xx = (float)m - 7.f; k[m] = expf(-(xx * xx) / 8.f); s += k[m]; }
    #pragma unroll
    for (int m = 0; m < 15; m++) k[m] /= s;
}

// fused: sort buckets (determinism) + vertical blur — both indexed by cell
__global__ void k_prep(int* cellcnt, int* bucket, const float* eg, const float* rg, float* tmp) {
    int idx = blockIdx.x * blockDim.x + threadIdx.x;
    if (idx >= G * G) return;
    int n = cellcnt[idx]; if (n > CAP) n = CAP;
    cellcnt[idx] = n;
    for (int a = 1; a < n; a++) {
        int v = bucket[idx * CAP + a];
        int b = a - 1;
        while (b >= 0 && bucket[idx * CAP + b] > v) { bucket[idx * CAP + b + 1] = bucket[idx * CAP + b]; b--; }
        bucket[idx * CAP + b + 1] = v;
    }
    int x = idx & (G - 1), y = idx >> 8;
    float k[15]; gauss_weights(k);
    float acc = 0.f;
    #pragma unroll
    for (int m = 0; m < 15; m++) {
        int yy = y + m - 7;
        if ((unsigned)yy < G) {
            float img = eg[yy * G + x] + 0.5f * rg[yy * G + x];
            acc += img * k[m];
        }
    }
    tmp[idx] = acc;
}

// heterogeneous fusion: blocks [0,512) do A = S @ W_inf (16 rows each);
// blocks [512,768) do the horizontal blur pass.
__global__ void k_blurH_matA(const float* tmp, float* field, const float* S, const float* W, float* A_) {
    __shared__ float sh[4096 + 16 * 64];
    int t = threadIdx.x;
    if (blockIdx.x < 512) {
        float* Wl = sh;
        float* Sl = sh + 4096;
        const float4* W4 = (const float4*)W;
        float4* Wl4 = (float4*)Wl;
        for (int k = t; k < 1024; k += 256) Wl4[k] = W4[k];
        int row0 = blockIdx.x * 16;
        const float4* S4 = (const float4*)(S + row0 * 64);
        float4* Sl4 = (float4*)Sl;
        for (int k = t; k < 256; k += 256) Sl4[k] = S4[k];
        __syncthreads();
        int c = t & 63, r0 = (t >> 6) * 4;
        #pragma unroll
        for (int rr = 0; rr < 4; rr++) {
            float acc = 0.f;
            #pragma unroll
            for (int k = 0; k < 64; k++) acc += Sl[(r0 + rr) * 64 + k] * Wl[k * 64 + c];
            A_[(row0 + r0 + rr) * 64 + c] = acc;
        }
    } else {
        int idx = (blockIdx.x - 512) * 256 + t;
        int x = idx & (G - 1), y = idx >> 8;
        float k[15]; gauss_weights(k);
        float acc = 0.f;
        #pragma unroll
        for (int m = 0; m < 15; m++) {
            int xx = x + m - 7;
            if ((unsigned)xx < G) acc += tmp[y * G + xx] * k[m];
        }
        field[idx] = acc;
    }
}

__device__ __forceinline__ float fast_tanh(float x) {
    float t = __expf(2.f * x);
    return 1.f - 2.f / (t + 1.f);   // correct limits at +-inf
}

// map k in [0,81) to (ox,oy) with ox^2+oy^2 <= 25, row-major by oy
__device__ __forceinline__ void cell_of(int k, int& ox, int& oy, int& d2) {
    const int w[11] = {1, 7, 9, 9, 9, 11, 9, 9, 9, 7, 1};
    int acc = 0; ox = 0; oy = 0;
    #pragma unroll
    for (int r = 0; r < 11; r++) {
        bool in = (k >= acc) && (k < acc + w[r]);
        if (in) { oy = r - 5; ox = k - acc - (w[r] >> 1); }
        acc += w[r];
    }
    d2 = ox * ox + oy * oy;
}

#define NB_WAVES 4
__global__ __launch_bounds__(256) void k_neighbors(
        const int* pos, const int* roles, const float* S, const float* A_,
        const int* cellcnt, const int* bucket,
        float* outsum, float* insum, int* nnbr, int* massn, int* fin, int* tgtb) {
    __shared__ int   lds_list[NB_WAVES][656];
    __shared__ float lds_si[NB_WAVES][64];
    __shared__ float lds_ai[NB_WAVES][64];
    int wid = threadIdx.x >> 6, lane = threadIdx.x & 63;
    int i = blockIdx.x * NB_WAVES + wid;
    int xi = pos[2 * i], yi = pos[2 * i + 1];
    lds_si[wid][lane] = S[i * 64 + lane];
    lds_ai[wid][lane] = A_[i * 64 + lane];

    // ---- phase 1: lane-parallel scan of the 81 candidate cells ----
    int cnt0 = 0, cnt1 = 0, c0 = 0, c1 = 0, d2_0 = 0, d2_1 = 0;
    {
        int ox, oy, d2; cell_of(lane, ox, oy, d2);
        int cx = xi + ox, cy = yi + oy;
        if ((unsigned)cx < G && (unsigned)cy < G) { c0 = cy * G + cx; d2_0 = d2; cnt0 = cellcnt[c0]; }
    }
    if (lane < 17) {
        int ox, oy, d2; cell_of(64 + lane, ox, oy, d2);
        int cx = xi + ox, cy = yi + oy;
        if ((unsigned)cx < G && (unsigned)cy < G) { c1 = cy * G + cx; d2_1 = d2; cnt1 = cellcnt[c1]; }
    }
    int x0 = cnt0;
    #pragma unroll
    for (int d = 1; d < 64; d <<= 1) { int y = __shfl_up(x0, d, 64); if (lane >= d) x0 += y; }
    int excl0 = x0 - cnt0, total0 = __shfl(x0, 63, 64);
    int x1 = cnt1;
    #pragma unroll
    for (int d = 1; d < 64; d <<= 1) { int y = __shfl_up(x1, d, 64); if (lane >= d) x1 += y; }
    int excl1 = x1 - cnt1, total1 = __shfl(x1, 63, 64);
    int nn_raw = total0 + total1;
    for (int s = 0; s < cnt0; s++) {
        int j = bucket[c0 * CAP + s];
        lds_list[wid][excl0 + s] = (d2_0 << 13) | j;
    }
    for (int s = 0; s < cnt1; s++) {
        int j = bucket[c1 * CAP + s];
        lds_list[wid][total0 + excl1 + s] = (d2_1 << 13) | j;
    }
    __syncthreads();

    // ---- phase 2: lane = neighbor entry ----
    float osum_p = 0.f, isum_p = 0.f;
    int nn = 0, mn = 0, fn = 0, bestkey = 0x7FFFFFFF;
    const float4* S4 = (const float4*)S;
    const float4* A4 = (const float4*)A_;
    const float4* si4 = (const float4*)lds_si[wid];
    const float4* ai4 = (const float4*)lds_ai[wid];
    for (int base = 0; base < nn_raw; base += 64) {
        int e = base + lane;
        bool inrange = e < nn_raw;
        int key = inrange ? lds_list[wid][e] : 0;
        int j = key & 8191;
        bool valid = inrange && (j != i);
        int rj = valid ? roles[j] : -1;
        nn += __popcll(__ballot(valid));
        mn += __popcll(__ballot(rj == 0));
        fn += __popcll(__ballot(rj == 1));
        int cand = (rj == 1) ? key : 0x7FFFFFFF;
        #pragma unroll
        for (int m = 32; m >= 1; m >>= 1) cand = min(cand, __shfl_xor(cand, m, 64));
        bestkey = min(bestkey, cand);
        if (valid) {
            const float4* srow = S4 + j * 16;
            const float4* arow = A4 + j * 16;
            float po0 = 0.f, po1 = 0.f, pi0 = 0.f, pi1 = 0.f;
            #pragma unroll
            for (int k = 0; k < 16; k += 2) {
                float4 sj = srow[k],     aj = arow[k];
                float4 av = ai4[k],      sv = si4[k];
                po0 += sj.x * av.x + sj.y * av.y + sj.z * av.z + sj.w * av.w;
                pi0 += aj.x * sv.x + aj.y * sv.y + aj.z * sv.z + aj.w * sv.w;
                float4 sj1 = srow[k + 1], aj1 = arow[k + 1];
                float4 av1 = ai4[k + 1],  sv1 = si4[k + 1];
                po1 += sj1.x * av1.x + sj1.y * av1.y + sj1.z * av1.z + sj1.w * av1.w;
                pi1 += aj1.x * sv1.x + aj1.y * sv1.y + aj1.z * sv1.z + aj1.w * sv1.w;
            }
            osum_p += fast_tanh(po0 + po1);
            isum_p += fast_tanh(pi0 + pi1);
        }
    }
    #pragma unroll
    for (int m = 32; m >= 1; m >>= 1) {
        osum_p += __shfl_xor(osum_p, m, 64);
        isum_p += __shfl_xor(isum_p, m, 64);
    }
    if (lane == 0) {
        outsum[i] = osum_p; insum[i] = isum_p;
        nnbr[i] = nn; massn[i] = mn; fin[i] = fn;
        tgtb[i] = (bestkey == 0x7FFFFFFF) ? 0 : (bestkey & 8191);
    }
}

// h = tanh(v @ W1 + b1), v = [states + 0.1*tanh(states@W_self), field[pos]]
// __launch_bounds__(256,2): 2 waves/EU min -> VGPR cap 256, prevents the
// 64-VGPR occupancy-heuristic allocation that spilled ~580 B/thread to scratch.
#define MLP1_A 16
__global__ __launch_bounds__(256, 2) void k_mlp1(
        const float* S, const float* Wself, const float* W1, const float* b1,
        const int* pos, const float* field, float* hbuf) {
    __shared__ float Ws[4096];       // 16 KB
    __shared__ float W1l[65 * 128];  // 33.3 KB
    __shared__ float Sl[MLP1_A][64]; // 4 KB
    __shared__ float v[MLP1_A][65];  // 4.2 KB
    int t = threadIdx.x;
    {
        const float4* Ws4 = (const float4*)Wself;
        float4* Wsl4 = (float4*)Ws;
        for (int k = t; k < 1024; k += 256) Wsl4[k] = Ws4[k];
        const float4* W14 = (const float4*)W1;
        float4* W1l4 = (float4*)W1l;
        for (int k = t; k < 2080; k += 256) W1l4[k] = W14[k];
    }
    int a0 = blockIdx.x * MLP1_A;
    {
        const float4* S4 = (const float4*)(S + a0 * 64);
        float4* Sl4 = (float4*)Sl;
        for (int k = t; k < MLP1_A * 16; k += 256) Sl4[k] = S4[k];
    }
    __syncthreads();
    for (int e = t; e < MLP1_A * 65; e += 256) {
        int a = e / 65, k = e % 65;
        float val;
        if (k == 64) {
            int ai = a0 + a;
            int x = pos[2 * ai], y = pos[2 * ai + 1];
            val = field[y * G + x];
        } else {
            float acc = 0.f;
            #pragma unroll
            for (int kk = 0; kk < 64; kk++) acc += Sl[a][kk] * Ws[kk * 64 + k];
            val = Sl[a][k] + 0.1f * tanhf(acc);
        }
        v[a][k] = val;
    }
    __syncthreads();
    #pragma unroll
    for (int aa = 0; aa < MLP1_A / 2; aa++) {
        int a = aa * 2 + (t >> 7), h = t & 127;
        float acc = b1[h];
        #pragma unroll
        for (int k = 0; k < 65; k++) acc += v[a][k] * W1l[k * 128 + h];
        hbuf[(a0 + a) * 128 + h] = tanhf(acc);
    }
}

// new_states = has ? (h @ W2 + b2 + 0.3*s) : s   + fused per-agent final logic
#define MLP2_A 16
__global__ __launch_bounds__(256, 2) void k_mlp2f(
        const float* hbuf, const float* W2, const float* b2, const float* S,
        const int* pos, const int* roles, const float* energies, const float* field,
        const float* outsum, const float* insum,
        const int* nnbr, const int* massn, const int* fin, const int* tgtb,
        float* out_states, float* out_e, float* out_roles, float* out_pos) {
    __shared__ float W2l[128 * 64];    // 32 KB
    __shared__ float hl[MLP2_A][128];  // 8 KB
    int t = threadIdx.x;
    {
        const float4* W24 = (const float4*)W2;
        float4* W2l4 = (float4*)W2l;
        for (int k = t; k < 2048; k += 256) W2l4[k] = W24[k];
    }
    int a0 = blockIdx.x * MLP2_A;
    {
        const float4* hb4 = (const float4*)(hbuf + a0 * 128);
        float4* hl4 = (float4*)hl;
        for (int k = t; k < MLP2_A * 32; k += 256) hl4[k] = hb4[k];
    }
    __syncthreads();
    #pragma unroll
    for (int aa = 0; aa < MLP2_A / 4; aa++) {
        int a = aa * 4 + (t >> 6), d = t & 63;
        int i = a0 + a;
        float acc = b2[d];
        #pragma unroll
        for (int k = 0; k < 128; k++) acc += hl[a][k] * W2l[k * 64 + d];
        bool has = nnbr[i] > 0;
        float s = S[i * 64 + d];
        out_states[i * 64 + d] = has ? (acc + 0.3f * s) : s;
    }
    if (t < MLP2_A) {
        int i = a0 + t;
        int x = pos[2 * i], y = pos[2 * i + 1];
        float f = field[y * G + x];
        float gx = (x == 0)     ? field[y * G + 1] - field[y * G + 0]
                 : (x == G - 1) ? field[y * G + G - 1] - field[y * G + G - 2]
                                : 0.5f * (field[y * G + x + 1] - field[y * G + x - 1]);
        float gy = (y == 0)     ? field[G + x] - field[x]
                 : (y == G - 1) ? field[(G - 1) * G + x] - field[(G - 2) * G + x]
                                : 0.5f * (field[(y + 1) * G + x] - field[(y - 1) * G + x]);
        int nn = nnbr[i];
        bool has = nn > 0;
        float denom = (float)max(nn, 1);
        float net = has ? (outsum[i] / denom - insum[i] / denom) : 0.f;
        int role = roles[i];
        float e = energies[i];
        int mn = massn[i], fn = fin[i];
        float e_fi = e + 0.02f * (float)mn;
        float e_other = e * 0.995f + 0.05f * fmaxf(f, 0.f) + ((mn >= 3) ? 0.02f : 0.f);
        float new_e = ((role == 1) ? e_fi : e_other) + 0.02f * fmaxf(net, 0.f);
        new_e = fminf(fmaxf(new_e, 0.f), 1.f);
        float score = net + 0.5f;
        int r0 = ((new_e > 0.7f) && (mn >= 2) && ((fn == 0) || (score > 0.2f))) ? 1 : 0;
        int r1 = ((mn < 1) || (new_e < 0.2f) || (score < -0.3f)) ? 0 : 1;
        int r2 = ((fn > 0) && (net > 0.5f)) ? 1 : ((new_e < 0.2f) ? 0 : 2);
        int nr = (role == 0) ? r0 : (role == 1) ? r1 : r2;
        bool move_mass = (nr == 0) && ((fabsf(gx) > 0.01f) || (fabsf(gy) > 0.01f));
        int dxm = (gx > 0.f) ? 1 : ((gx < 0.f) ? -1 : 0);
        int dym = (gy > 0.f) ? 1 : ((gy < 0.f) ? -1 : 0);
        int tj = tgtb[i];
        int tx = pos[2 * tj], ty = pos[2 * tj + 1];
        int dxc = (tx > x) ? 1 : ((tx < x) ? -1 : 0);
        int dyc = (ty > y) ? 1 : ((ty < y) ? -1 : 0);
        bool move_c = (nr == 2) && (fn > 0);
        int dx = move_mass ? dxm : (move_c ? dxc : 0);
        int dy = move_mass ? dym : (move_c ? dyc : 0);
        int nx = min(max(x + dx, 0), G - 1);
        int ny = min(max(y + dy, 0), G - 1);
        out_e[i] = new_e;
        out_roles[i] = (float)nr;
        out_pos[2 * i] = (float)nx;
        out_pos[2 * i + 1] = (float)ny;
    }
}

extern "C" void kernel_launch(void* const* d_in, const int* in_sizes, int n_in,
                              void* d_out, int out_size, void* d_ws, size_t ws_size,
                              hipStream_t stream) {
    const int*   positions = (const int*)d_in[0];
    const float* states    = (const float*)d_in[1];
    const int*   roles     = (const int*)d_in[2];
    const float* energies  = (const float*)d_in[3];
    const float* W_inf     = (const float*)d_in[4];
    const float* W_self    = (const float*)d_in[5];
    const float* W1        = (const float*)d_in[6];
    const float* b1        = (const float*)d_in[7];
    const float* W2        = (const float*)d_in[8];
    const float* b2        = (const float*)d_in[9];

    float* wsf = (float*)d_ws;
    int*   wsi = (int*)d_ws;

    float* eg      = wsf + OFF_EGRID;
    float* rg      = wsf + OFF_RGRID;
    float* tmp     = wsf + OFF_TMP;
    float* field   = wsf + OFF_FIELD;
    float* A_      = wsf + OFF_A;
    float* hbuf    = wsf + OFF_HBUF;
    float* outsum  = wsf + OFF_OUTSUM;
    float* insum   = wsf + OFF_INSUM;
    int*   nnbr    = wsi + OFF_NNBR;
    int*   massn   = wsi + OFF_MASSN;
    int*   fin     = wsi + OFF_FIN;
    int*   tgtb    = wsi + OFF_TGT;
    int*   cellcnt = wsi + OFF_CELLCNT;
    int*   bucket  = wsi + OFF_BUCKET;

    float* out_states = (float*)d_out;                 // N*D
    float* out_e      = out_states + N * D;            // N
    float* out_roles  = out_e + N;                     // N
    float* out_pos    = out_roles + N;                 // N*2

    k_zero<<<G * G / 256, 256, 0, stream>>>(eg, rg, cellcnt);
    k_scatter<<<N / 256, 256, 0, stream>>>(positions, roles, energies, eg, rg, cellcnt, bucket);
    k_prep<<<G * G / 256, 256, 0, stream>>>(cellcnt, bucket, eg, rg, tmp);
    k_blurH_matA<<<512 + 256, 256, 0, stream>>>(tmp, field, states, W_inf, A_);
    k_neighbors<<<N / NB_WAVES, 256, 0, stream>>>(positions, roles, states, A_, cellcnt, bucket,
                                                  outsum, insum, nnbr, massn, fin, tgtb);
    k_mlp1<<<N / MLP1_A, 256, 0, stream>>>(states, W_self, W1, b1, positions, field, hbuf);
    k_mlp2f<<<N / MLP2_A, 256, 0, stream>>>(hbuf, W2, b2, states,
                                            positions, roles, energies, field, outsum, insum,
                                            nnbr, massn, fin, tgtb,
                                            out_states, out_e, out_roles, out_pos);
}

// Round 8
// 73.948 us; speedup vs baseline: 1.9009x; 1.1268x over previous
//
#include <hip/hip_runtime.h>

#define N 8192
#define G 256
#define D 64
#define H 128
#define CAP 8

// ---- workspace word offsets ----
#define OFF_EGRID   0
#define OFF_RGRID   65536
#define OFF_FIELD   196608
#define OFF_A       262144     // 8192*64
#define OFF_OUTSUM  1843200
#define OFF_INSUM   1851392
#define OFF_NNBR    1859584
#define OFF_MASSN   1867776
#define OFF_FIN     1875968
#define OFF_TGT     1884160
#define OFF_CELLCNT 1892352
#define OFF_BUCKET  1957888    // 65536*CAP -> end 2482176 words (~9.5 MB)

__global__ void k_zero(float* eg, float* rg, int* cellcnt) {
    int i = blockIdx.x * blockDim.x + threadIdx.x;
    if (i < G * G) { eg[i] = 0.f; rg[i] = 0.f; cellcnt[i] = 0; }
}

__global__ void k_scatter(const int* pos, const int* roles, const float* energies,
                          float* eg, float* rg, int* cellcnt, int* bucket) {
    int i = blockIdx.x * blockDim.x + threadIdx.x;
    if (i >= N) return;
    int x = pos[2 * i], y = pos[2 * i + 1];
    int c = y * G + x;
    atomicMax((int*)&eg[c], __float_as_int(energies[i]));          // non-negative floats
    atomicMax((int*)&rg[c], __float_as_int((float)roles[i]));
    int slot = atomicAdd(&cellcnt[c], 1);
    if (slot < CAP) bucket[c * CAP + slot] = i;
}

__device__ __forceinline__ void gauss_weights(float* k) {
    float s = 0.f;
    #pragma unroll
    for (int m = 0; m < 15; m++) { float xx = (float)m - 7.f; k[m] = expf(-(xx * xx) / 8.f); s += k[m]; }
    #pragma unroll
    for (int m = 0; m < 15; m++) k[m] /= s;
}

// heterogeneous fusion:
//   blocks [0,256):  per-row bucket-sort (determinism) + blurV->LDS + blurH -> field
//   blocks [256,768): A = S @ W_inf (16 rows per block)
__global__ void k_prepall(int* cellcnt, int* bucket, const float* eg, const float* rg,
                          float* field, const float* S, const float* W, float* A_) {
    __shared__ float sh[4096 + 1024];   // matA: W(4096)+S(1024); blur uses sh[0..255]
    int t = threadIdx.x;
    if (blockIdx.x < 256) {
        int y = blockIdx.x, x = t;
        int idx = y * G + x;
        // bucket sort (ascending agent index) for deterministic neighbor order
        int n = cellcnt[idx]; if (n > CAP) n = CAP;
        cellcnt[idx] = n;
        for (int a = 1; a < n; a++) {
            int v = bucket[idx * CAP + a];
            int b = a - 1;
            while (b >= 0 && bucket[idx * CAP + b] > v) { bucket[idx * CAP + b + 1] = bucket[idx * CAP + b]; b--; }
            bucket[idx * CAP + b + 1] = v;
        }
        float k[15]; gauss_weights(k);
        float acc = 0.f;
        #pragma unroll
        for (int m = 0; m < 15; m++) {
            int yy = y + m - 7;
            if ((unsigned)yy < G) acc += (eg[yy * G + x] + 0.5f * rg[yy * G + x]) * k[m];
        }
        sh[x] = acc;
        __syncthreads();
        float acc2 = 0.f;
        #pragma unroll
        for (int m = 0; m < 15; m++) {
            int xx = x + m - 7;
            if ((unsigned)xx < G) acc2 += sh[xx] * k[m];
        }
        field[idx] = acc2;
    } else {
        float* Wl = sh;
        float* Sl = sh + 4096;
        const float4* W4 = (const float4*)W;
        float4* Wl4 = (float4*)Wl;
        for (int k = t; k < 1024; k += 256) Wl4[k] = W4[k];
        int row0 = (blockIdx.x - 256) * 16;
        const float4* S4 = (const float4*)(S + row0 * 64);
        float4* Sl4 = (float4*)Sl;
        for (int k = t; k < 256; k += 256) Sl4[k] = S4[k];
        __syncthreads();
        int c = t & 63, r0 = (t >> 6) * 4;
        #pragma unroll
        for (int rr = 0; rr < 4; rr++) {
            float acc = 0.f;
            #pragma unroll
            for (int k = 0; k < 64; k++) acc += Sl[(r0 + rr) * 64 + k] * Wl[k * 64 + c];
            A_[(row0 + r0 + rr) * 64 + c] = acc;
        }
    }
}

__device__ __forceinline__ float fast_tanh(float x) {
    float t = __expf(2.f * x);
    return 1.f - 2.f / (t + 1.f);   // correct limits at +-inf
}

// map k in [0,81) to (ox,oy) with ox^2+oy^2 <= 25, row-major by oy
__device__ __forceinline__ void cell_of(int k, int& ox, int& oy, int& d2) {
    const int w[11] = {1, 7, 9, 9, 9, 11, 9, 9, 9, 7, 1};
    int acc = 0; ox = 0; oy = 0;
    #pragma unroll
    for (int r = 0; r < 11; r++) {
        bool in = (k >= acc) && (k < acc + w[r]);
        if (in) { oy = r - 5; ox = k - acc - (w[r] >> 1); }
        acc += w[r];
    }
    d2 = ox * ox + oy * oy;
}

#define NB_WAVES 4
__global__ __launch_bounds__(256) void k_neighbors(
        const int* pos, const int* roles, const float* S, const float* A_,
        const int* cellcnt, const int* bucket,
        float* outsum, float* insum, int* nnbr, int* massn, int* fin, int* tgtb) {
    __shared__ int   lds_list[NB_WAVES][656];
    __shared__ float lds_si[NB_WAVES][64];
    __shared__ float lds_ai[NB_WAVES][64];
    int wid = threadIdx.x >> 6, lane = threadIdx.x & 63;
    int i = blockIdx.x * NB_WAVES + wid;
    int xi = pos[2 * i], yi = pos[2 * i + 1];
    lds_si[wid][lane] = S[i * 64 + lane];
    lds_ai[wid][lane] = A_[i * 64 + lane];

    // ---- phase 1: lane-parallel scan of the 81 candidate cells ----
    int cnt0 = 0, cnt1 = 0, c0 = 0, c1 = 0, d2_0 = 0, d2_1 = 0;
    {
        int ox, oy, d2; cell_of(lane, ox, oy, d2);
        int cx = xi + ox, cy = yi + oy;
        if ((unsigned)cx < G && (unsigned)cy < G) { c0 = cy * G + cx; d2_0 = d2; cnt0 = cellcnt[c0]; }
    }
    if (lane < 17) {
        int ox, oy, d2; cell_of(64 + lane, ox, oy, d2);
        int cx = xi + ox, cy = yi + oy;
        if ((unsigned)cx < G && (unsigned)cy < G) { c1 = cy * G + cx; d2_1 = d2; cnt1 = cellcnt[c1]; }
    }
    int x0 = cnt0;
    #pragma unroll
    for (int d = 1; d < 64; d <<= 1) { int y = __shfl_up(x0, d, 64); if (lane >= d) x0 += y; }
    int excl0 = x0 - cnt0, total0 = __shfl(x0, 63, 64);
    int x1 = cnt1;
    #pragma unroll
    for (int d = 1; d < 64; d <<= 1) { int y = __shfl_up(x1, d, 64); if (lane >= d) x1 += y; }
    int excl1 = x1 - cnt1, total1 = __shfl(x1, 63, 64);
    int nn_raw = total0 + total1;
    for (int s = 0; s < cnt0; s++) {
        int j = bucket[c0 * CAP + s];
        lds_list[wid][excl0 + s] = (d2_0 << 13) | j;
    }
    for (int s = 0; s < cnt1; s++) {
        int j = bucket[c1 * CAP + s];
        lds_list[wid][total0 + excl1 + s] = (d2_1 << 13) | j;
    }
    __syncthreads();

    // ---- phase 2: lane = neighbor entry ----
    float osum_p = 0.f, isum_p = 0.f;
    int nn = 0, mn = 0, fn = 0, bestkey = 0x7FFFFFFF;
    const float4* S4 = (const float4*)S;
    const float4* A4 = (const float4*)A_;
    const float4* si4 = (const float4*)lds_si[wid];
    const float4* ai4 = (const float4*)lds_ai[wid];
    for (int base = 0; base < nn_raw; base += 64) {
        int e = base + lane;
        bool inrange = e < nn_raw;
        int key = inrange ? lds_list[wid][e] : 0;
        int j = key & 8191;
        bool valid = inrange && (j != i);
        int rj = valid ? roles[j] : -1;
        nn += __popcll(__ballot(valid));
        mn += __popcll(__ballot(rj == 0));
        fn += __popcll(__ballot(rj == 1));
        int cand = (rj == 1) ? key : 0x7FFFFFFF;
        #pragma unroll
        for (int m = 32; m >= 1; m >>= 1) cand = min(cand, __shfl_xor(cand, m, 64));
        bestkey = min(bestkey, cand);
        if (valid) {
            const float4* srow = S4 + j * 16;
            const float4* arow = A4 + j * 16;
            float po0 = 0.f, po1 = 0.f, pi0 = 0.f, pi1 = 0.f;
            #pragma unroll
            for (int k = 0; k < 16; k += 2) {
                float4 sj = srow[k],     aj = arow[k];
                float4 av = ai4[k],      sv = si4[k];
                po0 += sj.x * av.x + sj.y * av.y + sj.z * av.z + sj.w * av.w;
                pi0 += aj.x * sv.x + aj.y * sv.y + aj.z * sv.z + aj.w * sv.w;
                float4 sj1 = srow[k + 1], aj1 = arow[k + 1];
                float4 av1 = ai4[k + 1],  sv1 = si4[k + 1];
                po1 += sj1.x * av1.x + sj1.y * av1.y + sj1.z * av1.z + sj1.w * av1.w;
                pi1 += aj1.x * sv1.x + aj1.y * sv1.y + aj1.z * sv1.z + aj1.w * sv1.w;
            }
            osum_p += fast_tanh(po0 + po1);
            isum_p += fast_tanh(pi0 + pi1);
        }
    }
    #pragma unroll
    for (int m = 32; m >= 1; m >>= 1) {
        osum_p += __shfl_xor(osum_p, m, 64);
        isum_p += __shfl_xor(isum_p, m, 64);
    }
    if (lane == 0) {
        outsum[i] = osum_p; insum[i] = isum_p;
        nnbr[i] = nn; massn[i] = mn; fin[i] = fn;
        tgtb[i] = (bestkey == 0x7FFFFFFF) ? 0 : (bestkey & 8191);
    }
}

// fused MLP: phase A selfpat->v, phase B h=tanh(v@W1+b1), phase C out=h@W2+b2,
// + per-agent final logic. One 33KB LDS weight buffer re-staged per phase.
// __launch_bounds__(256,2): VGPR cap 256, prevents the 64-VGPR spill (R6 lesson).
#define MLP_A 16
__global__ __launch_bounds__(256, 2) void k_mlp(
        const float* S, const float* Wself, const float* W1, const float* b1,
        const float* W2, const float* b2,
        const int* pos, const int* roles, const float* energies, const float* field,
        const float* outsum, const float* insum,
        const int* nnbr, const int* massn, const int* fin, const int* tgtb,
        float* out_states, float* out_e, float* out_roles, float* out_pos) {
    __shared__ float Wbuf[65 * 128];   // 33.3 KB: Wself(4096) -> W1(8320) -> W2(8192)
    __shared__ float Sl[MLP_A][64];    // 4 KB (kept live through phase C)
    __shared__ float v[MLP_A][65];     // 4.2 KB
    __shared__ float hl[MLP_A][128];   // 8 KB
    int t = threadIdx.x;
    int a0 = blockIdx.x * MLP_A;
    {
        const float4* w4 = (const float4*)Wself;
        float4* d4 = (float4*)Wbuf;
        for (int k = t; k < 1024; k += 256) d4[k] = w4[k];
        const float4* s4 = (const float4*)(S + a0 * 64);
        float4* sl4 = (float4*)Sl;
        for (int k = t; k < MLP_A * 16; k += 256) sl4[k] = s4[k];
    }
    __syncthreads();
    // phase A: v = [S + 0.1*tanh(S@Wself), field[pos]]
    for (int e = t; e < MLP_A * 65; e += 256) {
        int a = e / 65, k = e % 65;
        float val;
        if (k == 64) {
            int ai = a0 + a;
            int x = pos[2 * ai], y = pos[2 * ai + 1];
            val = field[y * G + x];
        } else {
            float acc = 0.f;
            #pragma unroll
            for (int kk = 0; kk < 64; kk++) acc += Sl[a][kk] * Wbuf[kk * 64 + k];
            val = Sl[a][k] + 0.1f * tanhf(acc);
        }
        v[a][k] = val;
    }
    __syncthreads();
    {
        const float4* w4 = (const float4*)W1;
        float4* d4 = (float4*)Wbuf;
        for (int k = t; k < 2080; k += 256) d4[k] = w4[k];
    }
    __syncthreads();
    // phase B: h = tanh(v @ W1 + b1)
    #pragma unroll
    for (int aa = 0; aa < MLP_A / 2; aa++) {
        int a = aa * 2 + (t >> 7), h = t & 127;
        float acc = b1[h];
        #pragma unroll
        for (int k = 0; k < 65; k++) acc += v[a][k] * Wbuf[k * 128 + h];
        hl[a][h] = tanhf(acc);
    }
    __syncthreads();
    {
        const float4* w4 = (const float4*)W2;
        float4* d4 = (float4*)Wbuf;
        for (int k = t; k < 2048; k += 256) d4[k] = w4[k];
    }
    __syncthreads();
    // phase C: out_states = has ? h@W2+b2 + 0.3*s : s
    #pragma unroll
    for (int aa = 0; aa < MLP_A / 4; aa++) {
        int a = aa * 4 + (t >> 6), d = t & 63;
        int i = a0 + a;
        float acc = b2[d];
        #pragma unroll
        for (int k = 0; k < 128; k++) acc += hl[a][k] * Wbuf[k * 64 + d];
        bool has = nnbr[i] > 0;
        float s = Sl[a][d];
        out_states[i * 64 + d] = has ? (acc + 0.3f * s) : s;
    }
    // per-agent final logic (energy, role, movement)
    if (t < MLP_A) {
        int i = a0 + t;
        int x = pos[2 * i], y = pos[2 * i + 1];
        float f = field[y * G + x];
        float gx = (x == 0)     ? field[y * G + 1] - field[y * G + 0]
                 : (x == G - 1) ? field[y * G + G - 1] - field[y * G + G - 2]
                                : 0.5f * (field[y * G + x + 1] - field[y * G + x - 1]);
        float gy = (y == 0)     ? field[G + x] - field[x]
                 : (y == G - 1) ? field[(G - 1) * G + x] - field[(G - 2) * G + x]
                                : 0.5f * (field[(y + 1) * G + x] - field[(y - 1) * G + x]);
        int nn = nnbr[i];
        bool has = nn > 0;
        float denom = (float)max(nn, 1);
        float net = has ? (outsum[i] / denom - insum[i] / denom) : 0.f;
        int role = roles[i];
        float e = energies[i];
        int mn = massn[i], fn = fin[i];
        float e_fi = e + 0.02f * (float)mn;
        float e_other = e * 0.995f + 0.05f * fmaxf(f, 0.f) + ((mn >= 3) ? 0.02f : 0.f);
        float new_e = ((role == 1) ? e_fi : e_other) + 0.02f * fmaxf(net, 0.f);
        new_e = fminf(fmaxf(new_e, 0.f), 1.f);
        float score = net + 0.5f;
        int r0 = ((new_e > 0.7f) && (mn >= 2) && ((fn == 0) || (score > 0.2f))) ? 1 : 0;
        int r1 = ((mn < 1) || (new_e < 0.2f) || (score < -0.3f)) ? 0 : 1;
        int r2 = ((fn > 0) && (net > 0.5f)) ? 1 : ((new_e < 0.2f) ? 0 : 2);
        int nr = (role == 0) ? r0 : (role == 1) ? r1 : r2;
        bool move_mass = (nr == 0) && ((fabsf(gx) > 0.01f) || (fabsf(gy) > 0.01f));
        int dxm = (gx > 0.f) ? 1 : ((gx < 0.f) ? -1 : 0);
        int dym = (gy > 0.f) ? 1 : ((gy < 0.f) ? -1 : 0);
        int tj = tgtb[i];
        int tx = pos[2 * tj], ty = pos[2 * tj + 1];
        int dxc = (tx > x) ? 1 : ((tx < x) ? -1 : 0);
        int dyc = (ty > y) ? 1 : ((ty < y) ? -1 : 0);
        bool move_c = (nr == 2) && (fn > 0);
        int dx = move_mass ? dxm : (move_c ? dxc : 0);
        int dy = move_mass ? dym : (move_c ? dyc : 0);
        int nx = min(max(x + dx, 0), G - 1);
        int ny = min(max(y + dy, 0), G - 1);
        out_e[i] = new_e;
        out_roles[i] = (float)nr;
        out_pos[2 * i] = (float)nx;
        out_pos[2 * i + 1] = (float)ny;
    }
}

extern "C" void kernel_launch(void* const* d_in, const int* in_sizes, int n_in,
                              void* d_out, int out_size, void* d_ws, size_t ws_size,
                              hipStream_t stream) {
    const int*   positions = (const int*)d_in[0];
    const float* states    = (const float*)d_in[1];
    const int*   roles     = (const int*)d_in[2];
    const float* energies  = (const float*)d_in[3];
    const float* W_inf     = (const float*)d_in[4];
    const float* W_self    = (const float*)d_in[5];
    const float* W1        = (const float*)d_in[6];
    const float* b1        = (const float*)d_in[7];
    const float* W2        = (const float*)d_in[8];
    const float* b2        = (const float*)d_in[9];

    float* wsf = (float*)d_ws;
    int*   wsi = (int*)d_ws;

    float* eg      = wsf + OFF_EGRID;
    float* rg      = wsf + OFF_RGRID;
    float* field   = wsf + OFF_FIELD;
    float* A_      = wsf + OFF_A;
    float* outsum  = wsf + OFF_OUTSUM;
    float* insum   = wsf + OFF_INSUM;
    int*   nnbr    = wsi + OFF_NNBR;
    int*   massn   = wsi + OFF_MASSN;
    int*   fin     = wsi + OFF_FIN;
    int*   tgtb    = wsi + OFF_TGT;
    int*   cellcnt = wsi + OFF_CELLCNT;
    int*   bucket  = wsi + OFF_BUCKET;

    float* out_states = (float*)d_out;                 // N*D
    float* out_e      = out_states + N * D;            // N
    float* out_roles  = out_e + N;                     // N
    float* out_pos    = out_roles + N;                 // N*2

    k_zero<<<G * G / 256, 256, 0, stream>>>(eg, rg, cellcnt);
    k_scatter<<<N / 256, 256, 0, stream>>>(positions, roles, energies, eg, rg, cellcnt, bucket);
    k_prepall<<<256 + 512, 256, 0, stream>>>(cellcnt, bucket, eg, rg, field, states, W_inf, A_);
    k_neighbors<<<N / NB_WAVES, 256, 0, stream>>>(positions, roles, states, A_, cellcnt, bucket,
                                                  outsum, insum, nnbr, massn, fin, tgtb);
    k_mlp<<<N / MLP_A, 256, 0, stream>>>(states, W_self, W1, b1, W2, b2,
                                         positions, roles, energies, field, outsum, insum,
                                         nnbr, massn, fin, tgtb,
                                         out_states, out_e, out_roles, out_pos);
}